// Round 4
// baseline (394.895 us; speedup 1.0000x reference)
//
#include <hip/hip_runtime.h>
#include <hip/hip_bf16.h>

// B=4, H=16, S=2048, D=64
//   S = mask ? -1e9 : QK^T/8 ; O = S@V ; out = log_softmax(O, dim=-1)
// v3: software-pipelined K-loop. Register prefetch of K/V (issued one full
// iteration ahead), double-buffered sK/sVt with ONE barrier per iteration
// (write -> barrier -> compute), mask int4 regs hoisted to iteration top,
// Q fragments loaded directly from global (registers for whole kernel).

typedef __attribute__((ext_vector_type(8))) short bf16x8;
typedef __attribute__((ext_vector_type(16))) float f32x16;

#define NEGV (-1e9f)

__device__ inline unsigned cvt_bf16(float f) {
    unsigned u = __builtin_bit_cast(unsigned, f);
    u += 0x7FFFu + ((u >> 16) & 1u);   // RNE (no NaNs in this problem)
    return u >> 16;
}
__device__ inline unsigned pk_bf16(float a, float b) {
    return cvt_bf16(a) | (cvt_bf16(b) << 16);
}

__global__ __launch_bounds__(256, 2)
void attn_kernel(const float* __restrict__ Q, const float* __restrict__ K,
                 const float* __restrict__ V, const int* __restrict__ M,
                 float* __restrict__ Out) {
    // pitch 72 shorts (36 dwords, 36 mod 32 = 4): all patterns bank-floor.
    __shared__ __attribute__((aligned(16))) unsigned short sS[256 * 72];       // 36 KB, S tiles (wave-private rows)
    __shared__ __attribute__((aligned(16))) unsigned short sK[2][64 * 72];     // 18.4 KB dbuf
    __shared__ __attribute__((aligned(16))) unsigned short sVt[2][64 * 72];    // 18.4 KB dbuf (V^T: [d][k])
    // total 73.7 KB -> 2 blocks/CU

    const int tid  = threadIdx.x;
    const int wave = tid >> 6;
    const int lane = tid & 63;
    const int half = lane >> 5;
    const int l32  = lane & 31;

    const int bid = blockIdx.x;
    const int h  = bid & 15;            // h innermost: 16 blocks share a mask tile
    const int qt = (bid >> 4) & 7;
    const int b  = bid >> 7;
    const int bh = b * 16 + h;
    const int q0 = qt * 256;

    const float* Qb = Q + (size_t)(bh * 2048 + q0) * 64;
    const float* Kb = K + (size_t)bh * 2048 * 64;
    const float* Vb = V + (size_t)bh * 2048 * 64;
    const int*   Mb = M + (size_t)(b * 2048 + q0) * 2048;

    // ---- prefetch registers for K/V staging (loaded one iter ahead) ----
    float4 kp[4];
    float  vp[16];
    const int krow = tid >> 4, kc4 = tid & 15;            // this thread's K-stage slot (4 rows apart)
    {   // tile 0
        const int k0 = 0;
#pragma unroll
        for (int i = 0; i < 4; i++)
            kp[i] = *(const float4*)(Kb + (size_t)(k0 + krow + i * 16) * 64 + kc4 * 4);
#pragma unroll
        for (int i = 0; i < 2; i++) {
            const int kb = (wave * 2 + i) * 8;
#pragma unroll
            for (int j = 0; j < 8; j++)
                vp[i * 8 + j] = Vb[(size_t)(k0 + kb + j) * 64 + lane];
        }
    }

    // ---- Q fragments direct from global (pre-scaled by 1/8), live all kernel ----
    // qF[qb][dk] elem j = Q[q0 + wave*64 + qb*32 + l32][dk*16 + half*8 + j] / 8
    bf16x8 qF[2][4];
#pragma unroll
    for (int qb = 0; qb < 2; qb++) {
        const float* qr = Qb + (size_t)(wave * 64 + qb * 32 + l32) * 64 + half * 8;
#pragma unroll
        for (int dk = 0; dk < 4; dk++) {
            const float4 f0 = *(const float4*)(qr + dk * 16);
            const float4 f1 = *(const float4*)(qr + dk * 16 + 4);
            union { bf16x8 v; unsigned u[4]; } t;
            t.u[0] = pk_bf16(f0.x * 0.125f, f0.y * 0.125f);
            t.u[1] = pk_bf16(f0.z * 0.125f, f0.w * 0.125f);
            t.u[2] = pk_bf16(f1.x * 0.125f, f1.y * 0.125f);
            t.u[3] = pk_bf16(f1.z * 0.125f, f1.w * 0.125f);
            qF[qb][dk] = t.v;
        }
    }

    f32x16 Oacc[2][2];
#pragma unroll
    for (int qb = 0; qb < 2; qb++)
#pragma unroll
        for (int db = 0; db < 2; db++)
#pragma unroll
            for (int r = 0; r < 16; r++) Oacc[qb][db][r] = 0.f;

    for (int ki = 0; ki < 32; ki++) {
        const int k0  = ki * 64;
        const int cur = ki & 1;

        // ---- mask regs for THIS iter: issued here, consumed mid-MFMA1 ----
        int4 mr[2][2][4];
#pragma unroll
        for (int jk = 0; jk < 2; jk++)
#pragma unroll
            for (int qb = 0; qb < 2; qb++) {
                const size_t mrow = (size_t)(wave * 64 + qb * 32 + l32) * 2048;
#pragma unroll
                for (int rg = 0; rg < 4; rg++)
                    mr[jk][qb][rg] = *(const int4*)&Mb[mrow + k0 + jk * 32 + half * 4 + rg * 8];
            }

        // ---- write prefetched tile ki into LDS buffer cur ----
#pragma unroll
        for (int i = 0; i < 4; i++) {
            uint2 p;
            p.x = pk_bf16(kp[i].x, kp[i].y);
            p.y = pk_bf16(kp[i].z, kp[i].w);
            *(uint2*)&sK[cur][(krow + i * 16) * 72 + kc4 * 4] = p;
        }
#pragma unroll
        for (int i = 0; i < 2; i++) {
            const int kb = (wave * 2 + i) * 8;
            uint4 p4;
            p4.x = pk_bf16(vp[i * 8 + 0], vp[i * 8 + 1]);
            p4.y = pk_bf16(vp[i * 8 + 2], vp[i * 8 + 3]);
            p4.z = pk_bf16(vp[i * 8 + 4], vp[i * 8 + 5]);
            p4.w = pk_bf16(vp[i * 8 + 6], vp[i * 8 + 7]);
            *(uint4*)&sVt[cur][lane * 72 + kb] = p4;
        }

        // ---- issue global loads for tile ki+1 (consumed next iter) ----
        if (ki < 31) {
            const int kn = k0 + 64;
#pragma unroll
            for (int i = 0; i < 4; i++)
                kp[i] = *(const float4*)(Kb + (size_t)(kn + krow + i * 16) * 64 + kc4 * 4);
#pragma unroll
            for (int i = 0; i < 2; i++) {
                const int kb = (wave * 2 + i) * 8;
#pragma unroll
                for (int j = 0; j < 8; j++)
                    vp[i * 8 + j] = Vb[(size_t)(kn + kb + j) * 64 + lane];
            }
        }

        __syncthreads();   // single barrier per iter: writes visible, prev reads done

        // ---- MFMA1: S^T[kk][q(wave)] = K * Q^T, mask, pack -> sS (wave rows) ----
        // A[m=l32][k=half*8+j] = K[k0+jk*32+l32][dk*16+half*8+j]
        // C: col=l32=q-in-32, row=(r&3)+8*(r>>2)+4*half = kk-in-32
#pragma unroll
        for (int jk = 0; jk < 2; jk++) {
            bf16x8 aK[4];
#pragma unroll
            for (int dk = 0; dk < 4; dk++)
                aK[dk] = *(const bf16x8*)&sK[cur][(jk * 32 + l32) * 72 + dk * 16 + half * 8];
#pragma unroll
            for (int qb = 0; qb < 2; qb++) {
                f32x16 acc;
#pragma unroll
                for (int r = 0; r < 16; r++) acc[r] = 0.f;
#pragma unroll
                for (int dk = 0; dk < 4; dk++)
                    acc = __builtin_amdgcn_mfma_f32_32x32x16_bf16(aK[dk], qF[qb][dk], acc, 0, 0, 0);
                const int qrow = wave * 64 + qb * 32 + l32;   // tile-local q
#pragma unroll
                for (int rg = 0; rg < 4; rg++) {
                    const int4 mm = mr[jk][qb][rg];
                    const float v0 = mm.x ? NEGV : acc[rg * 4 + 0];
                    const float v1 = mm.y ? NEGV : acc[rg * 4 + 1];
                    const float v2 = mm.z ? NEGV : acc[rg * 4 + 2];
                    const float v3 = mm.w ? NEGV : acc[rg * 4 + 3];
                    uint2 p; p.x = pk_bf16(v0, v1); p.y = pk_bf16(v2, v3);
                    // wave-private rows: no barrier needed (same-wave DS in order)
                    *(uint2*)&sS[qrow * 72 + jk * 32 + rg * 8 + half * 4] = p;
                }
            }
        }

        // ---- MFMA2: O[q][d] += S @ V ----
#pragma unroll
        for (int kkb = 0; kkb < 4; kkb++) {
            bf16x8 bV[2];
#pragma unroll
            for (int db = 0; db < 2; db++)
                bV[db] = *(const bf16x8*)&sVt[cur][(db * 32 + l32) * 72 + kkb * 16 + half * 8];
#pragma unroll
            for (int qb = 0; qb < 2; qb++) {
                const bf16x8 aS = *(const bf16x8*)&sS[(wave * 64 + qb * 32 + l32) * 72 + kkb * 16 + half * 8];
#pragma unroll
                for (int db = 0; db < 2; db++)
                    Oacc[qb][db] = __builtin_amdgcn_mfma_f32_32x32x16_bf16(aS, bV[db], Oacc[qb][db], 0, 0, 0);
            }
        }
    }

    // ---- epilogue: log_softmax over d=64 ----
    // Oacc: q-in-32 = (r&3)+8*(r>>2)+4*half, d = db*32+l32.
    float* Ob = Out + (size_t)bh * 2048 * 64;
#pragma unroll
    for (int qb = 0; qb < 2; qb++) {
#pragma unroll
        for (int r = 0; r < 16; r++) {
            const float v0 = Oacc[qb][0][r], v1 = Oacc[qb][1][r];
            float mx = fmaxf(v0, v1);
#pragma unroll
            for (int off = 1; off < 32; off <<= 1)
                mx = fmaxf(mx, __shfl_xor(mx, off, 64));
            float s = __expf(v0 - mx) + __expf(v1 - mx);
#pragma unroll
            for (int off = 1; off < 32; off <<= 1)
                s += __shfl_xor(s, off, 64);
            const float lse = mx + __logf(s);
            const int qrow = q0 + wave * 64 + qb * 32 + (r & 3) + 8 * (r >> 2) + 4 * half;
            Ob[(size_t)qrow * 64 + l32]      = v0 - lse;
            Ob[(size_t)qrow * 64 + 32 + l32] = v1 - lse;
        }
    }
}

extern "C" void kernel_launch(void* const* d_in, const int* in_sizes, int n_in,
                              void* d_out, int out_size, void* d_ws, size_t ws_size,
                              hipStream_t stream) {
    const float* Q = (const float*)d_in[0];
    const float* K = (const float*)d_in[1];
    const float* V = (const float*)d_in[2];
    const int*   M = (const int*)d_in[3];
    float* Out = (float*)d_out;

    dim3 grid(512);    // 4*16 bh * 8 q-tiles; 2 blocks/CU -> fully resident
    dim3 block(256);
    attn_kernel<<<grid, block, 0, stream>>>(Q, K, V, M, Out);
}

// Round 5
// 327.582 us; speedup vs baseline: 1.2055x; 1.2055x over previous
//
#include <hip/hip_runtime.h>
#include <hip/hip_bf16.h>

// B=4, H=16, S=2048, D=64
//   S = mask ? -1e9 : QK^T/8 ; O = S@V ; out = log_softmax(O, dim=-1)
// v4: fixes v3's fatal flaw — __syncthreads drains vmcnt(0), so prefetch
// must be ISSUED AFTER the barrier (consumed before the next one). Also
// 1-VALU truncating bf16 packs (v_perm) for K and S; V/Q stay RNE.

typedef __attribute__((ext_vector_type(8))) short bf16x8;
typedef __attribute__((ext_vector_type(16))) float f32x16;

#define NEGV (-1e9f)

__device__ inline unsigned cvt_bf16(float f) {
    unsigned u = __builtin_bit_cast(unsigned, f);
    u += 0x7FFFu + ((u >> 16) & 1u);   // RNE
    return u >> 16;
}
__device__ inline unsigned pk_bf16(float a, float b) {       // RNE pack
    return cvt_bf16(a) | (cvt_bf16(b) << 16);
}
__device__ inline unsigned pk_trunc(float a, float b) {      // 1 v_perm_b32
    return __builtin_amdgcn_perm(__builtin_bit_cast(unsigned, b),
                                 __builtin_bit_cast(unsigned, a), 0x07060302u);
}

__global__ __launch_bounds__(256, 2)
void attn_kernel(const float* __restrict__ Q, const float* __restrict__ K,
                 const float* __restrict__ V, const int* __restrict__ M,
                 float* __restrict__ Out) {
    // pitch 72 shorts (36 dwords, 36 mod 32 = 4): all patterns bank-floor.
    __shared__ __attribute__((aligned(16))) unsigned short sS[256 * 72];       // 36 KB (wave-private rows)
    __shared__ __attribute__((aligned(16))) unsigned short sK[2][64 * 72];     // 18.4 KB dbuf
    __shared__ __attribute__((aligned(16))) unsigned short sVt[2][64 * 72];    // 18.4 KB dbuf (V^T)
    // total 73.7 KB -> 2 blocks/CU

    const int tid  = threadIdx.x;
    const int wave = tid >> 6;
    const int lane = tid & 63;
    const int half = lane >> 5;
    const int l32  = lane & 31;

    const int bid = blockIdx.x;
    const int h  = bid & 15;            // 16 consecutive blocks share a mask tile
    const int qt = (bid >> 4) & 7;
    const int b  = bid >> 7;
    const int bh = b * 16 + h;
    const int q0 = qt * 256;

    const float* Qb = Q + (size_t)(bh * 2048 + q0) * 64;
    const float* Kb = K + (size_t)bh * 2048 * 64;
    const float* Vb = V + (size_t)bh * 2048 * 64;
    const int*   Mb = M + (size_t)(b * 2048 + q0) * 2048;

    // ---- prologue: prefetch K/V tile 0 into registers ----
    float4 kp[4];
    float  vp[16];
    const int krow = tid >> 4, kc4 = tid & 15;
#pragma unroll
    for (int i = 0; i < 4; i++)
        kp[i] = *(const float4*)(Kb + (size_t)(krow + i * 16) * 64 + kc4 * 4);
#pragma unroll
    for (int i = 0; i < 2; i++) {
        const int kb = (wave * 2 + i) * 8;
#pragma unroll
        for (int j = 0; j < 8; j++)
            vp[i * 8 + j] = Vb[(size_t)(kb + j) * 64 + lane];
    }

    // ---- Q fragments direct from global (pre-scaled by 1/8), RNE, live all kernel ----
    bf16x8 qF[2][4];
#pragma unroll
    for (int qb = 0; qb < 2; qb++) {
        const float* qr = Qb + (size_t)(wave * 64 + qb * 32 + l32) * 64 + half * 8;
#pragma unroll
        for (int dk = 0; dk < 4; dk++) {
            const float4 f0 = *(const float4*)(qr + dk * 16);
            const float4 f1 = *(const float4*)(qr + dk * 16 + 4);
            union { bf16x8 v; unsigned u[4]; } t;
            t.u[0] = pk_bf16(f0.x * 0.125f, f0.y * 0.125f);
            t.u[1] = pk_bf16(f0.z * 0.125f, f0.w * 0.125f);
            t.u[2] = pk_bf16(f1.x * 0.125f, f1.y * 0.125f);
            t.u[3] = pk_bf16(f1.z * 0.125f, f1.w * 0.125f);
            qF[qb][dk] = t.v;
        }
    }

    f32x16 Oacc[2][2];
#pragma unroll
    for (int qb = 0; qb < 2; qb++)
#pragma unroll
        for (int db = 0; db < 2; db++)
#pragma unroll
            for (int r = 0; r < 16; r++) Oacc[qb][db][r] = 0.f;

    for (int ki = 0; ki < 32; ki++) {
        const int k0  = ki * 64;
        const int cur = ki & 1;

        // ---- write prefetched tile ki into LDS[cur] (loads issued a full
        //      compute-phase ago -> vmcnt wait is cheap) ----
#pragma unroll
        for (int i = 0; i < 4; i++) {
            uint2 p;
            p.x = pk_trunc(kp[i].x, kp[i].y);
            p.y = pk_trunc(kp[i].z, kp[i].w);
            *(uint2*)&sK[cur][(krow + i * 16) * 72 + kc4 * 4] = p;
        }
#pragma unroll
        for (int i = 0; i < 2; i++) {
            const int kb = (wave * 2 + i) * 8;
            uint4 p4;
            p4.x = pk_bf16(vp[i * 8 + 0], vp[i * 8 + 1]);
            p4.y = pk_bf16(vp[i * 8 + 2], vp[i * 8 + 3]);
            p4.z = pk_bf16(vp[i * 8 + 4], vp[i * 8 + 5]);
            p4.w = pk_bf16(vp[i * 8 + 6], vp[i * 8 + 7]);
            *(uint4*)&sVt[cur][lane * 72 + kb] = p4;
        }

        __syncthreads();   // drain hits nothing in flight (all loads consumed)

        // ---- AFTER the barrier: issue this iter's mask loads (L2-hot,
        //      needed in ~150 cyc) then next tile's K/V prefetch (needed
        //      next iteration, before the next barrier -> never drained) ----
        int4 mr[2][2][4];
#pragma unroll
        for (int jk = 0; jk < 2; jk++)
#pragma unroll
            for (int qb = 0; qb < 2; qb++) {
                const size_t mrow = (size_t)(wave * 64 + qb * 32 + l32) * 2048;
#pragma unroll
                for (int rg = 0; rg < 4; rg++)
                    mr[jk][qb][rg] = *(const int4*)&Mb[mrow + k0 + jk * 32 + half * 4 + rg * 8];
            }

        if (ki < 31) {
            const int kn = k0 + 64;
#pragma unroll
            for (int i = 0; i < 4; i++)
                kp[i] = *(const float4*)(Kb + (size_t)(kn + krow + i * 16) * 64 + kc4 * 4);
#pragma unroll
            for (int i = 0; i < 2; i++) {
                const int kb = (wave * 2 + i) * 8;
#pragma unroll
                for (int j = 0; j < 8; j++)
                    vp[i * 8 + j] = Vb[(size_t)(kn + kb + j) * 64 + lane];
            }
        }

        // ---- MFMA1: S^T[kk][q(wave)] = K * Q^T, mask, trunc-pack -> sS ----
        // A[m=l32][k=half*8+j] = K[k0+jk*32+l32][dk*16+half*8+j]
        // C: col=l32=q-in-32, row=(r&3)+8*(r>>2)+4*half = kk-in-32
#pragma unroll
        for (int jk = 0; jk < 2; jk++) {
            bf16x8 aK[4];
#pragma unroll
            for (int dk = 0; dk < 4; dk++)
                aK[dk] = *(const bf16x8*)&sK[cur][(jk * 32 + l32) * 72 + dk * 16 + half * 8];
#pragma unroll
            for (int qb = 0; qb < 2; qb++) {
                f32x16 acc;
#pragma unroll
                for (int r = 0; r < 16; r++) acc[r] = 0.f;
#pragma unroll
                for (int dk = 0; dk < 4; dk++)
                    acc = __builtin_amdgcn_mfma_f32_32x32x16_bf16(aK[dk], qF[qb][dk], acc, 0, 0, 0);
                const int qrow = wave * 64 + qb * 32 + l32;   // tile-local q
#pragma unroll
                for (int rg = 0; rg < 4; rg++) {
                    const int4 mm = mr[jk][qb][rg];
                    const float v0 = mm.x ? NEGV : acc[rg * 4 + 0];
                    const float v1 = mm.y ? NEGV : acc[rg * 4 + 1];
                    const float v2 = mm.z ? NEGV : acc[rg * 4 + 2];
                    const float v3 = mm.w ? NEGV : acc[rg * 4 + 3];
                    uint2 p; p.x = pk_trunc(v0, v1); p.y = pk_trunc(v2, v3);
                    // wave-private rows: no barrier needed (same-wave DS in order)
                    *(uint2*)&sS[qrow * 72 + jk * 32 + rg * 8 + half * 4] = p;
                }
            }
        }

        // ---- MFMA2: O[q][d] += S @ V ----
#pragma unroll
        for (int kkb = 0; kkb < 4; kkb++) {
            bf16x8 bV[2];
#pragma unroll
            for (int db = 0; db < 2; db++)
                bV[db] = *(const bf16x8*)&sVt[cur][(db * 32 + l32) * 72 + kkb * 16 + half * 8];
#pragma unroll
            for (int qb = 0; qb < 2; qb++) {
                const bf16x8 aS = *(const bf16x8*)&sS[(wave * 64 + qb * 32 + l32) * 72 + kkb * 16 + half * 8];
#pragma unroll
                for (int db = 0; db < 2; db++)
                    Oacc[qb][db] = __builtin_amdgcn_mfma_f32_32x32x16_bf16(aS, bV[db], Oacc[qb][db], 0, 0, 0);
            }
        }
    }

    // ---- epilogue: log_softmax over d=64 ----
    float* Ob = Out + (size_t)bh * 2048 * 64;
#pragma unroll
    for (int qb = 0; qb < 2; qb++) {
#pragma unroll
        for (int r = 0; r < 16; r++) {
            const float v0 = Oacc[qb][0][r], v1 = Oacc[qb][1][r];
            float mx = fmaxf(v0, v1);
#pragma unroll
            for (int off = 1; off < 32; off <<= 1)
                mx = fmaxf(mx, __shfl_xor(mx, off, 64));
            float s = __expf(v0 - mx) + __expf(v1 - mx);
#pragma unroll
            for (int off = 1; off < 32; off <<= 1)
                s += __shfl_xor(s, off, 64);
            const float lse = mx + __logf(s);
            const int qrow = q0 + wave * 64 + qb * 32 + (r & 3) + 8 * (r >> 2) + 4 * half;
            Ob[(size_t)qrow * 64 + l32]      = v0 - lse;
            Ob[(size_t)qrow * 64 + 32 + l32] = v1 - lse;
        }
    }
}

extern "C" void kernel_launch(void* const* d_in, const int* in_sizes, int n_in,
                              void* d_out, int out_size, void* d_ws, size_t ws_size,
                              hipStream_t stream) {
    const float* Q = (const float*)d_in[0];
    const float* K = (const float*)d_in[1];
    const float* V = (const float*)d_in[2];
    const int*   M = (const int*)d_in[3];
    float* Out = (float*)d_out;

    dim3 grid(512);    // 4*16 bh * 8 q-tiles; 2 blocks/CU -> fully resident
    dim3 block(256);
    attn_kernel<<<grid, block, 0, stream>>>(Q, K, V, M, Out);
}

// Round 6
// 255.881 us; speedup vs baseline: 1.5433x; 1.2802x over previous
//
#include <hip/hip_runtime.h>
#include <hip/hip_bf16.h>

// B=4, H=16, S=2048, D=64
//   S = mask ? -1e9 : QK^T/8 ; O = S@V ; out = log_softmax(O, dim=-1)
// v5: kill the scattered mask gather (64 lines/instr x16 instrs!) —
// pre-kernel packs mask into transposed 64-bit row-words ([b][qt][ki][q],
// 67MB->2MB); main kernel fetches 1 coalesced u64/thread/iter and swaps
// qb-halves with one shfl_xor. v4 pipeline skeleton kept.

typedef __attribute__((ext_vector_type(8))) short bf16x8;
typedef __attribute__((ext_vector_type(16))) float f32x16;

#define NEGV (-1e9f)

__device__ inline unsigned cvt_bf16(float f) {
    unsigned u = __builtin_bit_cast(unsigned, f);
    u += 0x7FFFu + ((u >> 16) & 1u);   // RNE
    return u >> 16;
}
__device__ inline unsigned pk_bf16(float a, float b) {       // RNE pack
    return cvt_bf16(a) | (cvt_bf16(b) << 16);
}
__device__ inline unsigned pk_trunc(float a, float b) {      // 1 v_perm_b32
    return __builtin_amdgcn_perm(__builtin_bit_cast(unsigned, b),
                                 __builtin_bit_cast(unsigned, a), 0x07060302u);
}
__device__ inline unsigned long long shflx32_u64(unsigned long long x) {
    union { unsigned long long v; int i[2]; } u; u.v = x;
    u.i[0] = __shfl_xor(u.i[0], 32, 64);
    u.i[1] = __shfl_xor(u.i[1], 32, 64);
    return u.v;
}

// ---- pre-kernel: mask int32 [b][q][kk] -> bit-words bitT[b][qt][ki][q] ----
__global__ __launch_bounds__(256)
void mask_pack(const int* __restrict__ M, unsigned long long* __restrict__ bitT) {
    const int lane = threadIdx.x & 63;
    const int gw   = (blockIdx.x * 256 + threadIdx.x) >> 6;
    const int nw   = (gridDim.x * 256) >> 6;
    for (int w = gw; w < 4 * 8 * 32 * 256; w += nw) {
        const int q  = w & 255;
        const int ki = (w >> 8) & 31;
        const int qt = (w >> 13) & 7;
        const int b  = w >> 16;
        const int m  = M[((size_t)(b * 2048 + qt * 256 + q)) * 2048 + ki * 64 + lane];
        const unsigned long long bal = __ballot(m != 0);
        if (lane == 0) bitT[w] = bal;
    }
}

__global__ __launch_bounds__(256, 2)
void attn_kernel(const float* __restrict__ Q, const float* __restrict__ K,
                 const float* __restrict__ V,
                 const unsigned long long* __restrict__ bitT,
                 float* __restrict__ Out) {
    // pitch 72 shorts (36 dwords, 36 mod 32 = 4): all patterns bank-floor.
    __shared__ __attribute__((aligned(16))) unsigned short sS[256 * 72];       // 36 KB (wave-private rows)
    __shared__ __attribute__((aligned(16))) unsigned short sK[2][64 * 72];     // 18.4 KB dbuf
    __shared__ __attribute__((aligned(16))) unsigned short sVt[2][64 * 72];    // 18.4 KB dbuf (V^T)
    // total 73.7 KB -> 2 blocks/CU

    const int tid  = threadIdx.x;
    const int wave = tid >> 6;
    const int lane = tid & 63;
    const int half = lane >> 5;
    const int l32  = lane & 31;

    const int bid = blockIdx.x;
    const int h  = bid & 15;            // 16 consecutive blocks share a mask tile
    const int qt = (bid >> 4) & 7;
    const int b  = bid >> 7;
    const int bh = b * 16 + h;
    const int q0 = qt * 256;

    const float* Qb = Q + (size_t)(bh * 2048 + q0) * 64;
    const float* Kb = K + (size_t)bh * 2048 * 64;
    const float* Vb = V + (size_t)bh * 2048 * 64;
    const unsigned long long* Bt = bitT + (size_t)(b * 8 + qt) * 32 * 256
                                 + wave * 64 + half * 32 + l32;   // this lane's row-word slot

    // ---- prologue: prefetch K/V/mask tile 0 into registers ----
    float4 kp[4];
    float  vp[16];
    unsigned long long mw = Bt[0];
    const int krow = tid >> 4, kc4 = tid & 15;
#pragma unroll
    for (int i = 0; i < 4; i++)
        kp[i] = *(const float4*)(Kb + (size_t)(krow + i * 16) * 64 + kc4 * 4);
#pragma unroll
    for (int i = 0; i < 2; i++) {
        const int kb = (wave * 2 + i) * 8;
#pragma unroll
        for (int j = 0; j < 8; j++)
            vp[i * 8 + j] = Vb[(size_t)(kb + j) * 64 + lane];
    }

    // ---- Q fragments direct from global (pre-scaled by 1/8), RNE, live all kernel ----
    bf16x8 qF[2][4];
#pragma unroll
    for (int qb = 0; qb < 2; qb++) {
        const float* qr = Qb + (size_t)(wave * 64 + qb * 32 + l32) * 64 + half * 8;
#pragma unroll
        for (int dk = 0; dk < 4; dk++) {
            const float4 f0 = *(const float4*)(qr + dk * 16);
            const float4 f1 = *(const float4*)(qr + dk * 16 + 4);
            union { bf16x8 v; unsigned u[4]; } t;
            t.u[0] = pk_bf16(f0.x * 0.125f, f0.y * 0.125f);
            t.u[1] = pk_bf16(f0.z * 0.125f, f0.w * 0.125f);
            t.u[2] = pk_bf16(f1.x * 0.125f, f1.y * 0.125f);
            t.u[3] = pk_bf16(f1.z * 0.125f, f1.w * 0.125f);
            qF[qb][dk] = t.v;
        }
    }

    f32x16 Oacc[2][2];
#pragma unroll
    for (int qb = 0; qb < 2; qb++)
#pragma unroll
        for (int db = 0; db < 2; db++)
#pragma unroll
            for (int r = 0; r < 16; r++) Oacc[qb][db][r] = 0.f;

    for (int ki = 0; ki < 32; ki++) {
        const int k0  = ki * 64;
        const int cur = ki & 1;

        // ---- write prefetched tile ki into LDS[cur] ----
#pragma unroll
        for (int i = 0; i < 4; i++) {
            uint2 p;
            p.x = pk_trunc(kp[i].x, kp[i].y);
            p.y = pk_trunc(kp[i].z, kp[i].w);
            *(uint2*)&sK[cur][(krow + i * 16) * 72 + kc4 * 4] = p;
        }
#pragma unroll
        for (int i = 0; i < 2; i++) {
            const int kb = (wave * 2 + i) * 8;
            uint4 p4;
            p4.x = pk_bf16(vp[i * 8 + 0], vp[i * 8 + 1]);
            p4.y = pk_bf16(vp[i * 8 + 2], vp[i * 8 + 3]);
            p4.z = pk_bf16(vp[i * 8 + 4], vp[i * 8 + 5]);
            p4.w = pk_bf16(vp[i * 8 + 6], vp[i * 8 + 7]);
            *(uint4*)&sVt[cur][lane * 72 + kb] = p4;
        }

        __syncthreads();   // drain hits nothing in flight (all loads consumed)

        // ---- AFTER the barrier: issue next tile's prefetch (consumed before
        //      the next barrier -> never drained) ----
        unsigned long long mwN = 0;
        if (ki < 31) {
            const int kn = k0 + 64;
            mwN = Bt[(ki + 1) * 256];
#pragma unroll
            for (int i = 0; i < 4; i++)
                kp[i] = *(const float4*)(Kb + (size_t)(kn + krow + i * 16) * 64 + kc4 * 4);
#pragma unroll
            for (int i = 0; i < 2; i++) {
                const int kb = (wave * 2 + i) * 8;
#pragma unroll
                for (int j = 0; j < 8; j++)
                    vp[i * 8 + j] = Vb[(size_t)(kn + kb + j) * 64 + lane];
            }
        }

        // ---- exchange mask words: lane holds row (half-half); partner has the other qb ----
        const unsigned long long mwO = shflx32_u64(mw);
        const unsigned long long wQ0 = half ? mwO : mw;   // row wave*64 + l32
        const unsigned long long wQ1 = half ? mw  : mwO;  // row wave*64 + 32 + l32

        // ---- MFMA1: S^T[kk][q(wave)] = K * Q^T, mask bits, trunc-pack -> sS ----
        // A[m=l32][k=half*8+j] = K[k0+jk*32+l32][dk*16+half*8+j]
        // C: col=l32=q-in-32, row=(r&3)+8*(r>>2)+4*half = kk-in-32
        // bit index for acc[rg*4+w] = jk*32 + rg*8 + half*4 + w
#pragma unroll
        for (int jk = 0; jk < 2; jk++) {
            bf16x8 aK[4];
#pragma unroll
            for (int dk = 0; dk < 4; dk++)
                aK[dk] = *(const bf16x8*)&sK[cur][(jk * 32 + l32) * 72 + dk * 16 + half * 8];
#pragma unroll
            for (int qb = 0; qb < 2; qb++) {
                f32x16 acc;
#pragma unroll
                for (int r = 0; r < 16; r++) acc[r] = 0.f;
#pragma unroll
                for (int dk = 0; dk < 4; dk++)
                    acc = __builtin_amdgcn_mfma_f32_32x32x16_bf16(aK[dk], qF[qb][dk], acc, 0, 0, 0);
                const int qrow = wave * 64 + qb * 32 + l32;   // tile-local q
                const unsigned b32 = (unsigned)((qb ? wQ1 : wQ0) >> (jk * 32));
#pragma unroll
                for (int rg = 0; rg < 4; rg++) {
                    const unsigned nib = b32 >> (rg * 8 + half * 4);
                    const float v0 = (nib & 1u) ? NEGV : acc[rg * 4 + 0];
                    const float v1 = (nib & 2u) ? NEGV : acc[rg * 4 + 1];
                    const float v2 = (nib & 4u) ? NEGV : acc[rg * 4 + 2];
                    const float v3 = (nib & 8u) ? NEGV : acc[rg * 4 + 3];
                    uint2 p; p.x = pk_trunc(v0, v1); p.y = pk_trunc(v2, v3);
                    // wave-private rows: no barrier needed (same-wave DS in order)
                    *(uint2*)&sS[qrow * 72 + jk * 32 + rg * 8 + half * 4] = p;
                }
            }
        }

        // ---- MFMA2: O[q][d] += S @ V ----
#pragma unroll
        for (int kkb = 0; kkb < 4; kkb++) {
            bf16x8 bV[2];
#pragma unroll
            for (int db = 0; db < 2; db++)
                bV[db] = *(const bf16x8*)&sVt[cur][(db * 32 + l32) * 72 + kkb * 16 + half * 8];
#pragma unroll
            for (int qb = 0; qb < 2; qb++) {
                const bf16x8 aS = *(const bf16x8*)&sS[(wave * 64 + qb * 32 + l32) * 72 + kkb * 16 + half * 8];
#pragma unroll
                for (int db = 0; db < 2; db++)
                    Oacc[qb][db] = __builtin_amdgcn_mfma_f32_32x32x16_bf16(aS, bV[db], Oacc[qb][db], 0, 0, 0);
            }
        }

        mw = mwN;
    }

    // ---- epilogue: log_softmax over d=64 ----
    float* Ob = Out + (size_t)bh * 2048 * 64;
#pragma unroll
    for (int qb = 0; qb < 2; qb++) {
#pragma unroll
        for (int r = 0; r < 16; r++) {
            const float v0 = Oacc[qb][0][r], v1 = Oacc[qb][1][r];
            float mx = fmaxf(v0, v1);
#pragma unroll
            for (int off = 1; off < 32; off <<= 1)
                mx = fmaxf(mx, __shfl_xor(mx, off, 64));
            float s = __expf(v0 - mx) + __expf(v1 - mx);
#pragma unroll
            for (int off = 1; off < 32; off <<= 1)
                s += __shfl_xor(s, off, 64);
            const float lse = mx + __logf(s);
            const int qrow = q0 + wave * 64 + qb * 32 + (r & 3) + 8 * (r >> 2) + 4 * half;
            Ob[(size_t)qrow * 64 + l32]      = v0 - lse;
            Ob[(size_t)qrow * 64 + 32 + l32] = v1 - lse;
        }
    }
}

extern "C" void kernel_launch(void* const* d_in, const int* in_sizes, int n_in,
                              void* d_out, int out_size, void* d_ws, size_t ws_size,
                              hipStream_t stream) {
    const float* Q = (const float*)d_in[0];
    const float* K = (const float*)d_in[1];
    const float* V = (const float*)d_in[2];
    const int*   M = (const int*)d_in[3];
    float* Out = (float*)d_out;
    unsigned long long* bitT = (unsigned long long*)d_ws;   // needs 2 MB scratch

    mask_pack<<<dim3(4096), dim3(256), 0, stream>>>(M, bitT);
    attn_kernel<<<dim3(512), dim3(256), 0, stream>>>(Q, K, V, bitT, Out);
}